// Round 1
// 763.289 us; speedup vs baseline: 1.5267x; 1.5267x over previous
//
#include <hip/hip_runtime.h>
#include <hip/hip_bf16.h>
#include <math.h>

#define N_HIGH 4096
#define N_LOW 262144
#define E_HIGH 65536
#define E_LOW 524288
#define LN_EPS 1e-5f
#define ATT_SCALE 0.17677669529663687f /* 1/sqrt(32) */

typedef short bf16x8 __attribute__((ext_vector_type(8)));
typedef float f32x4 __attribute__((ext_vector_type(4)));

__device__ __forceinline__ float bf2f(unsigned int u) {
    union { unsigned int i; float f; } v; v.i = u << 16; return v.f;
}
__device__ __forceinline__ unsigned short f2bf(float f) {
    union { unsigned int i; float f; } v; v.f = f;
    unsigned int r = (v.i + 0x7fffu + ((v.i >> 16) & 1u)) >> 16;
    return (unsigned short)r;
}
__device__ __forceinline__ float ldf(const void* p, size_t i, int isbf) {
    if (isbf) return bf2f(((const unsigned short*)p)[i]);
    return ((const float*)p)[i];
}
__device__ __forceinline__ float4 load4f(const void* p, size_t i, int isbf) {
    if (isbf) {
        uint2 u = *(const uint2*)((const unsigned short*)p + i);
        float4 r;
        r.x = bf2f(u.x & 0xffffu); r.y = bf2f(u.x >> 16);
        r.z = bf2f(u.y & 0xffffu); r.w = bf2f(u.y >> 16);
        return r;
    }
    return *(const float4*)((const float*)p + i);
}
__device__ __forceinline__ void stf(void* p, size_t i, float v, int isbf) {
    if (isbf) ((unsigned short*)p)[i] = f2bf(v);
    else      ((float*)p)[i] = v;
}

// ---------------------------------------------------------------------------
// Dtype probe (proven): bits[8:15] of first 256 words.
// ---------------------------------------------------------------------------
__global__ __launch_bounds__(256) void probe_dtype_kernel(
    const unsigned int* __restrict__ x, int* __restrict__ flag)
{
    __shared__ int cnt;
    if (threadIdx.x == 0) cnt = 0;
    __syncthreads();
    unsigned int b = (x[threadIdx.x] >> 8) & 0x7fu;
    if (b >= 60u && b <= 65u) atomicAdd(&cnt, 1);
    __syncthreads();
    if (threadIdx.x == 0) *flag = (cnt >= 128) ? 1 : 0;
}

// ---------------------------------------------------------------------------
// Prep: Wt[g][n][k] = bf16(W_g[k][n]) — one-time transpose+convert.
// ---------------------------------------------------------------------------
__global__ __launch_bounds__(256) void prep_wt_kernel(
    const void* __restrict__ Wq, const void* __restrict__ Wk,
    const void* __restrict__ Wv, const void* __restrict__ Ws,
    unsigned short* __restrict__ Wt, const int* __restrict__ dflag)
{
    const int isbf = *dflag;
    const int g = blockIdx.x >> 3;
    const int slice = blockIdx.x & 7;
    const void* W = (g == 0) ? Wq : (g == 1) ? Wk : (g == 2) ? Wv : Ws;
    #pragma unroll
    for (int i = 0; i < 8; ++i) {
        int linear = i * 256 + threadIdx.x;
        int k = slice * 16 + (linear >> 7);
        int n = linear & 127;
        float v = ldf(W, (size_t)k * 128 + n, isbf);
        Wt[((size_t)g * 128 + n) * 128 + k] = f2bf(v);
    }
}

// ---------------------------------------------------------------------------
// MFMA projection GEMM (unchanged, proven). q,k,v -> bf16 qkv[M,384];
// skip -> fp32 accv[M,128].
// ---------------------------------------------------------------------------
__global__ __launch_bounds__(256) void gemm_mfma_kernel(
    const void* __restrict__ x, const unsigned short* __restrict__ Wt,
    const void* __restrict__ bq, const void* __restrict__ bk,
    const void* __restrict__ bv, const void* __restrict__ bs,
    unsigned short* __restrict__ qkv, float* __restrict__ accv,
    const int* __restrict__ dflag)
{
    __shared__ unsigned short As[64 * 136];
    __shared__ unsigned short Bs[128 * 136];
    const int isbf = *dflag;
    const int tid = threadIdx.x;
    const int m0 = blockIdx.x * 64;

    #pragma unroll
    for (int i = 0; i < 8; ++i) {
        int linear = i * 256 + tid;
        int row = linear >> 5;
        int c4 = (linear & 31) << 2;
        float4 v = load4f(x, (size_t)(m0 + row) * 128 + c4, isbf);
        ushort4 s;
        s.x = f2bf(v.x); s.y = f2bf(v.y); s.z = f2bf(v.z); s.w = f2bf(v.w);
        *(ushort4*)&As[row * 136 + c4] = s;
    }

    const void* blist[4] = { bq, bk, bv, bs };

    const int lane = tid & 63;
    const int w = tid >> 6;
    const int wm = (w & 1) * 32;
    const int wn = (w >> 1) * 64;
    const int lr = lane & 15;
    const int lk = (lane >> 4) * 8;
    const int rbase = (lane >> 4) * 4;

    for (int c = 0; c < 4; ++c) {
        __syncthreads();
        #pragma unroll
        for (int i = 0; i < 8; ++i) {
            int linear = i * 256 + tid;
            int n = linear >> 4;
            int c8 = (linear & 15) << 3;
            uint4 v = *(const uint4*)&Wt[((size_t)c * 128 + n) * 128 + c8];
            *(uint4*)&Bs[n * 136 + c8] = v;
        }
        __syncthreads();

        f32x4 acc[2][4];
        #pragma unroll
        for (int a = 0; a < 2; ++a)
            #pragma unroll
            for (int b = 0; b < 4; ++b) acc[a][b] = (f32x4){0.f, 0.f, 0.f, 0.f};

        #pragma unroll
        for (int kk = 0; kk < 4; ++kk) {
            int k0 = kk * 32 + lk;
            bf16x8 af[2], bfv[4];
            #pragma unroll
            for (int im = 0; im < 2; ++im)
                af[im] = *(const bf16x8*)&As[(wm + im * 16 + lr) * 136 + k0];
            #pragma unroll
            for (int in = 0; in < 4; ++in)
                bfv[in] = *(const bf16x8*)&Bs[(wn + in * 16 + lr) * 136 + k0];
            #pragma unroll
            for (int im = 0; im < 2; ++im)
                #pragma unroll
                for (int in = 0; in < 4; ++in)
                    acc[im][in] = __builtin_amdgcn_mfma_f32_16x16x32_bf16(
                        af[im], bfv[in], acc[im][in], 0, 0, 0);
        }

        float bias[4];
        #pragma unroll
        for (int in = 0; in < 4; ++in) bias[in] = ldf(blist[c], wn + in * 16 + lr, isbf);

        #pragma unroll
        for (int im = 0; im < 2; ++im) {
            #pragma unroll
            for (int r = 0; r < 4; ++r) {
                int m = wm + im * 16 + rbase + r;
                size_t row = (size_t)(m0 + m);
                #pragma unroll
                for (int in = 0; in < 4; ++in) {
                    int n = wn + in * 16 + lr;
                    float val = acc[im][in][r] + bias[in];
                    if (c < 3) qkv[row * 384 + c * 128 + n] = f2bf(val);
                    else       accv[row * 128 + n] = val;
                }
            }
        }
    }
}

// ---------------------------------------------------------------------------
// CSR build: count degrees -> exclusive scan -> fill (atomic cursor on off,
// so off becomes END offsets; start = end - deg).
// ---------------------------------------------------------------------------
__global__ __launch_bounds__(256) void count_deg_kernel(
    const int* __restrict__ ei, int E, int* __restrict__ deg)
{
    int e = blockIdx.x * 256 + threadIdx.x;
    if (e >= E) return;
    atomicAdd(&deg[ei[E + e]], 1);
}

// Block of 256 threads scans 1024 elements (4/thread). pre = in-block
// exclusive prefix; bsum[bid] = block total.
__global__ __launch_bounds__(256) void scan1_kernel(
    const int* __restrict__ deg, int* __restrict__ pre, int* __restrict__ bsum)
{
    __shared__ int wsum[4];
    int tid = threadIdx.x;
    int lane = tid & 63, w = tid >> 6;
    int base = blockIdx.x * 1024 + tid * 4;
    int4 v = *(const int4*)(deg + base);
    int s = v.x + v.y + v.z + v.w;
    int inc = s;
    #pragma unroll
    for (int m = 1; m < 64; m <<= 1) {
        int t = __shfl_up(inc, m, 64);
        if (lane >= m) inc += t;
    }
    if (lane == 63) wsum[w] = inc;
    __syncthreads();
    int woff = 0;
    #pragma unroll
    for (int j = 0; j < 4; ++j) if (j < w) woff += wsum[j];
    int excl = woff + inc - s;
    pre[base]     = excl;
    pre[base + 1] = excl + v.x;
    pre[base + 2] = excl + v.x + v.y;
    pre[base + 3] = excl + v.x + v.y + v.z;
    if (tid == 0) bsum[blockIdx.x] = wsum[0] + wsum[1] + wsum[2] + wsum[3];
}

__global__ void scan2_kernel(int* __restrict__ bsum, int NB)
{
    if (threadIdx.x == 0 && blockIdx.x == 0) {
        int run = 0;
        for (int i = 0; i < NB; ++i) { int t = bsum[i]; bsum[i] = run; run += t; }
    }
}

__global__ __launch_bounds__(256) void scan3_kernel(
    const int* __restrict__ pre, const int* __restrict__ bsum,
    int* __restrict__ off, int N)
{
    int i = blockIdx.x * 256 + threadIdx.x;
    if (i >= N) return;
    off[i] = pre[i] + bsum[i >> 10];
}

__global__ __launch_bounds__(256) void fill_csr_kernel(
    const int* __restrict__ ei, int E, int* __restrict__ off,
    int* __restrict__ csr)
{
    int e = blockIdx.x * 256 + threadIdx.x;
    if (e >= E) return;
    int dst = ei[E + e];
    int pos = atomicAdd(&off[dst], 1);
    csr[pos] = ei[e];
}

// ---------------------------------------------------------------------------
// Fused gather attention + skip + LayerNorm + ReLU. One wave per dst node;
// single-pass softmax (sum e*v / sum e), per-head via 16-lane shfl reduce.
// Output: bf16 row written into the fp32 skip buffer's own row (stride 256
// ushorts) — same-wave read-before-write makes the overlay safe.
// ---------------------------------------------------------------------------
__global__ __launch_bounds__(256) void attn_gather_ln_kernel(
    const unsigned short* __restrict__ qkv, const int* __restrict__ csr_src,
    const int* __restrict__ off_end, const int* __restrict__ deg,
    const float* skip, const void* __restrict__ lnw,
    const void* __restrict__ lnb, unsigned short* out, int N,
    const int* __restrict__ dflag)
{
    const int isbf = *dflag;
    int lane = threadIdx.x & 63;
    int n = blockIdx.x * 4 + (threadIdx.x >> 6);
    if (n >= N) return;
    int end = off_end[n];
    int cnt = deg[n];
    int p = end - cnt;

    ushort2 qv = *(const ushort2*)(qkv + (long)n * 384 + 2 * lane);
    float q0 = bf2f(qv.x), q1 = bf2f(qv.y);
    float den = 0.f, a0 = 0.f, a1 = 0.f;

    // 2-edge unrolled main loop: four independent 256B row loads in flight.
    for (; p + 1 < end; p += 2) {
        int s0 = csr_src[p], s1 = csr_src[p + 1];
        const unsigned short* b0 = qkv + (long)s0 * 384 + 2 * lane;
        const unsigned short* b1 = qkv + (long)s1 * 384 + 2 * lane;
        ushort2 k0 = *(const ushort2*)(b0 + 128);
        ushort2 k1 = *(const ushort2*)(b1 + 128);
        ushort2 v0 = *(const ushort2*)(b0 + 256);
        ushort2 v1 = *(const ushort2*)(b1 + 256);
        float p0 = q0 * bf2f(k0.x) + q1 * bf2f(k0.y);
        float p1 = q0 * bf2f(k1.x) + q1 * bf2f(k1.y);
        #pragma unroll
        for (int m = 1; m < 16; m <<= 1) {
            p0 += __shfl_xor(p0, m, 64);
            p1 += __shfl_xor(p1, m, 64);
        }
        float z0 = fminf(fmaxf(p0 * ATT_SCALE, -60.f), 60.f);
        float z1 = fminf(fmaxf(p1 * ATT_SCALE, -60.f), 60.f);
        float e0 = __expf(z0), e1 = __expf(z1);
        den += e0 + e1;
        a0 += e0 * bf2f(v0.x) + e1 * bf2f(v1.x);
        a1 += e0 * bf2f(v0.y) + e1 * bf2f(v1.y);
    }
    if (p < end) {
        int s0 = csr_src[p];
        const unsigned short* b0 = qkv + (long)s0 * 384 + 2 * lane;
        ushort2 k0 = *(const ushort2*)(b0 + 128);
        ushort2 v0 = *(const ushort2*)(b0 + 256);
        float p0 = q0 * bf2f(k0.x) + q1 * bf2f(k0.y);
        #pragma unroll
        for (int m = 1; m < 16; m <<= 1) p0 += __shfl_xor(p0, m, 64);
        float z0 = fminf(fmaxf(p0 * ATT_SCALE, -60.f), 60.f);
        float e0 = __expf(z0);
        den += e0;
        a0 += e0 * bf2f(v0.x);
        a1 += e0 * bf2f(v0.y);
    }

    float inv = (cnt > 0) ? 1.f / den : 0.f;
    float2 sk = *(const float2*)(skip + (long)n * 128 + 2 * lane);
    float x0 = a0 * inv + sk.x;
    float x1 = a1 * inv + sk.y;

    float s = x0 + x1, qq = x0 * x0 + x1 * x1;
    #pragma unroll
    for (int m = 1; m < 64; m <<= 1) {
        s += __shfl_xor(s, m, 64);
        qq += __shfl_xor(qq, m, 64);
    }
    float mean = s * (1.f / 128.f);
    float var = fmaxf(qq * (1.f / 128.f) - mean * mean, 0.f);
    float rs = rsqrtf(var + LN_EPS);
    float w0 = ldf(lnw, 2 * lane, isbf), w1 = ldf(lnw, 2 * lane + 1, isbf);
    float bb0 = ldf(lnb, 2 * lane, isbf), bb1 = ldf(lnb, 2 * lane + 1, isbf);
    float y0 = fmaxf((x0 - mean) * rs * w0 + bb0, 0.f);
    float y1 = fmaxf((x1 - mean) * rs * w1 + bb1, 0.f);
    unsigned short* o = out + (long)n * 256 + 2 * lane;
    o[0] = f2bf(y0);
    o[1] = f2bf(y1);
}

// ---------------------------------------------------------------------------
// global_mean_pool over sorted batch; one block (128 thr) per high node.
// l rows now stride 256 ushorts (bf16 interleaved in fp32 skip buffer).
// ---------------------------------------------------------------------------
__global__ __launch_bounds__(128) void pool_kernel(
    const unsigned short* __restrict__ l, const int* __restrict__ batch,
    float* __restrict__ pooled)
{
    __shared__ int se[2];
    int g = blockIdx.x;
    if (threadIdx.x == 0) {
        int lo = 0, hi = N_LOW;
        while (lo < hi) { int mid = (lo + hi) >> 1; if (batch[mid] < g) lo = mid + 1; else hi = mid; }
        se[0] = lo;
        hi = N_LOW;
        while (lo < hi) { int mid = (lo + hi) >> 1; if (batch[mid] < g + 1) lo = mid + 1; else hi = mid; }
        se[1] = lo;
    }
    __syncthreads();
    int start = se[0], end = se[1];
    int d = threadIdx.x;
    float ssum = 0.f;
    for (int r = start; r < end; ++r) ssum += bf2f(l[(long)r * 256 + d]);
    int cnt = end - start;
    pooled[(long)g * 128 + d] = ssum / (float)(cnt > 0 ? cnt : 1);
}

// ---------------------------------------------------------------------------
// high_out = sim*h + (1-sim)*pooled, sim = sigmoid([h,pooled]@w_lh)
// ---------------------------------------------------------------------------
__global__ __launch_bounds__(256) void high_out_kernel(
    const unsigned short* __restrict__ h, const float* __restrict__ pooled,
    const void* __restrict__ wlh, void* __restrict__ out,
    const int* __restrict__ dflag)
{
    const int isbf = *dflag;
    int lane = threadIdx.x & 63;
    int n = blockIdx.x * 4 + (threadIdx.x >> 6);
    if (n >= N_HIGH) return;
    float h0 = bf2f(h[(long)n * 256 + 2 * lane]);
    float h1 = bf2f(h[(long)n * 256 + 2 * lane + 1]);
    float2 pv = *(const float2*)(pooled + (long)n * 128 + 2 * lane);
    float s = h0 * ldf(wlh, 2 * lane, isbf) + h1 * ldf(wlh, 2 * lane + 1, isbf)
            + pv.x * ldf(wlh, 128 + 2 * lane, isbf) + pv.y * ldf(wlh, 128 + 2 * lane + 1, isbf);
    #pragma unroll
    for (int m = 1; m < 64; m <<= 1) s += __shfl_xor(s, m, 64);
    float sim = 1.f / (1.f + __expf(-s));
    stf(out, (size_t)n * 128 + 2 * lane,     sim * h0 + (1.f - sim) * pv.x, isbf);
    stf(out, (size_t)n * 128 + 2 * lane + 1, sim * h1 + (1.f - sim) * pv.y, isbf);
}

// ---------------------------------------------------------------------------
// low_out = a*l + (1-a)*h[batch], a = sigmoid([hb,l]@w_hl)
// ---------------------------------------------------------------------------
__global__ __launch_bounds__(256) void low_out_kernel(
    const unsigned short* __restrict__ l, const unsigned short* __restrict__ h,
    const int* __restrict__ batch, const void* __restrict__ whl,
    void* __restrict__ out, const int* __restrict__ dflag)
{
    const int isbf = *dflag;
    int lane = threadIdx.x & 63;
    int n = blockIdx.x * 4 + (threadIdx.x >> 6);
    if (n >= N_LOW) return;
    int g = batch[n];
    float l0 = bf2f(l[(long)n * 256 + 2 * lane]);
    float l1 = bf2f(l[(long)n * 256 + 2 * lane + 1]);
    float h0 = bf2f(h[(long)g * 256 + 2 * lane]);
    float h1 = bf2f(h[(long)g * 256 + 2 * lane + 1]);
    float s = h0 * ldf(whl, 2 * lane, isbf) + h1 * ldf(whl, 2 * lane + 1, isbf)
            + l0 * ldf(whl, 128 + 2 * lane, isbf) + l1 * ldf(whl, 128 + 2 * lane + 1, isbf);
    #pragma unroll
    for (int m = 1; m < 64; m <<= 1) s += __shfl_xor(s, m, 64);
    float a = 1.f / (1.f + __expf(-s));
    size_t base = (size_t)N_HIGH * 128 + (size_t)n * 128 + 2 * lane;
    stf(out, base,     a * l0 + (1.f - a) * h0, isbf);
    stf(out, base + 1, a * l1 + (1.f - a) * h1, isbf);
}

// ---------------------------------------------------------------------------
extern "C" void kernel_launch(void* const* d_in, const int* in_sizes, int n_in,
                              void* d_out, int out_size, void* d_ws, size_t ws_size,
                              hipStream_t stream)
{
    const void* high_emb = d_in[0];
    const void* low_emb  = d_in[1];
    const void* Wq = d_in[2];  const void* bq = d_in[3];
    const void* Wk = d_in[4];  const void* bk = d_in[5];
    const void* Wv = d_in[6];  const void* bv = d_in[7];
    const void* Ws = d_in[8];  const void* bs = d_in[9];
    const void* ln_w = d_in[10];
    const void* ln_b = d_in[11];
    const void* w_lh = d_in[12];
    const void* w_hl = d_in[13];
    const int* ei_high = (const int*)d_in[14];
    const int* ei_low  = (const int*)d_in[15];
    const int* batch   = (const int*)d_in[16];

    // Workspace layout (bytes). WS_NEEDED unchanged from the proven layout.
    char* ws = (char*)d_ws;
    const size_t OFF_QKV_LOW  = 0;           // bf16 [N_LOW,384]
    const size_t OFF_ACC_LOW  = 201326592;   // f32 skip [N_LOW,128]; bf16 l overlays rows
    const size_t OFF_AUX      = 335544320;   // Wt + CSR scratch (old e/den region)
    const size_t OFF_QKV_HIGH = 348127232;   // bf16 [N_HIGH,384]
    const size_t OFF_ACC_HIGH = 351272960;   // f32 skip [N_HIGH,128]; bf16 h overlays rows
    const size_t OFF_POOLED   = 354484224;   // f32 [N_HIGH,128]
    const size_t OFF_FLAG     = 356581376;   // int dtype flag
    const size_t WS_NEEDED    = 356581632;
    if (ws_size < WS_NEEDED) return;

    unsigned short* qkv_low  = (unsigned short*)(ws + OFF_QKV_LOW);
    float*          acc_low  = (float*)(ws + OFF_ACC_LOW);
    unsigned short* qkv_high = (unsigned short*)(ws + OFF_QKV_HIGH);
    float*          acc_high = (float*)(ws + OFF_ACC_HIGH);
    float*          pooled   = (float*)(ws + OFF_POOLED);
    int*            dflag    = (int*)(ws + OFF_FLAG);

    // AUX region carve-up (all 16B aligned):
    unsigned short* Wt       = (unsigned short*)(ws + OFF_AUX);          // 131072 B (256KB reserved)
    int* deg_low  = (int*)(ws + OFF_AUX +  262144);                      // 1 MB
    int* pre_low  = (int*)(ws + OFF_AUX + 1310720);                      // 1 MB
    int* off_low  = (int*)(ws + OFF_AUX + 2359296);                      // 1 MB
    int* csr_low  = (int*)(ws + OFF_AUX + 3407872);                      // 2 MB
    int* deg_high = (int*)(ws + OFF_AUX + 5505024);                      // 16 KB
    int* pre_high = (int*)(ws + OFF_AUX + 5521408);                      // 16 KB
    int* off_high = (int*)(ws + OFF_AUX + 5537792);                      // 16 KB
    int* csr_high = (int*)(ws + OFF_AUX + 5554176);                      // 256 KB
    int* bsum     = (int*)(ws + OFF_AUX + 5816320);                      // 4 KB

    // bf16 overlays (stride 256 ushorts) inside the fp32 skip buffers
    unsigned short* l_low  = (unsigned short*)acc_low;
    unsigned short* h_high = (unsigned short*)acc_high;

    hipMemsetAsync(deg_low, 0, (size_t)N_LOW * sizeof(int), stream);
    hipMemsetAsync(deg_high, 0, (size_t)N_HIGH * sizeof(int), stream);

    probe_dtype_kernel<<<1, 256, 0, stream>>>((const unsigned int*)high_emb, dflag);

    // CSR build (independent of gemm; cheap)
    count_deg_kernel<<<E_LOW / 256, 256, 0, stream>>>(ei_low, E_LOW, deg_low);
    count_deg_kernel<<<E_HIGH / 256, 256, 0, stream>>>(ei_high, E_HIGH, deg_high);

    scan1_kernel<<<N_LOW / 1024, 256, 0, stream>>>(deg_low, pre_low, bsum);
    scan2_kernel<<<1, 64, 0, stream>>>(bsum, N_LOW / 1024);
    scan3_kernel<<<N_LOW / 256, 256, 0, stream>>>(pre_low, bsum, off_low, N_LOW);

    scan1_kernel<<<N_HIGH / 1024, 256, 0, stream>>>(deg_high, pre_high, bsum);
    scan2_kernel<<<1, 64, 0, stream>>>(bsum, N_HIGH / 1024);
    scan3_kernel<<<N_HIGH / 256, 256, 0, stream>>>(pre_high, bsum, off_high, N_HIGH);

    fill_csr_kernel<<<E_LOW / 256, 256, 0, stream>>>(ei_low, E_LOW, off_low, csr_low);
    fill_csr_kernel<<<E_HIGH / 256, 256, 0, stream>>>(ei_high, E_HIGH, off_high, csr_high);
    // off_* now holds END offsets; start = end - deg.

    prep_wt_kernel<<<32, 256, 0, stream>>>(Wq, Wk, Wv, Ws, Wt, dflag);

    gemm_mfma_kernel<<<N_HIGH / 64, 256, 0, stream>>>(
        high_emb, Wt, bq, bk, bv, bs, qkv_high, acc_high, dflag);
    gemm_mfma_kernel<<<N_LOW / 64, 256, 0, stream>>>(
        low_emb, Wt, bq, bk, bv, bs, qkv_low, acc_low, dflag);

    attn_gather_ln_kernel<<<N_HIGH / 4, 256, 0, stream>>>(
        qkv_high, csr_high, off_high, deg_high, acc_high, ln_w, ln_b,
        h_high, N_HIGH, dflag);
    attn_gather_ln_kernel<<<N_LOW / 4, 256, 0, stream>>>(
        qkv_low, csr_low, off_low, deg_low, acc_low, ln_w, ln_b,
        l_low, N_LOW, dflag);

    pool_kernel<<<N_HIGH, 128, 0, stream>>>(l_low, batch, pooled);

    high_out_kernel<<<N_HIGH / 4, 256, 0, stream>>>(h_high, pooled, w_lh, d_out, dflag);
    low_out_kernel<<<N_LOW / 4, 256, 0, stream>>>(l_low, h_high, batch, w_hl, d_out, dflag);
}

// Round 3
// 615.151 us; speedup vs baseline: 1.8943x; 1.2408x over previous
//
#include <hip/hip_runtime.h>
#include <hip/hip_bf16.h>
#include <math.h>

#define N_HIGH 4096
#define N_LOW 262144
#define E_HIGH 65536
#define E_LOW 524288
#define LN_EPS 1e-5f
#define ATT_SCALE 0.17677669529663687f /* 1/sqrt(32) */

typedef short bf16x8 __attribute__((ext_vector_type(8)));
typedef float f32x4 __attribute__((ext_vector_type(4)));

__device__ __forceinline__ float bf2f(unsigned int u) {
    union { unsigned int i; float f; } v; v.i = u << 16; return v.f;
}
__device__ __forceinline__ unsigned short f2bf(float f) {
    union { unsigned int i; float f; } v; v.f = f;
    unsigned int r = (v.i + 0x7fffu + ((v.i >> 16) & 1u)) >> 16;
    return (unsigned short)r;
}
__device__ __forceinline__ float ldf(const void* p, size_t i, int isbf) {
    if (isbf) return bf2f(((const unsigned short*)p)[i]);
    return ((const float*)p)[i];
}
__device__ __forceinline__ float4 load4f(const void* p, size_t i, int isbf) {
    if (isbf) {
        uint2 u = *(const uint2*)((const unsigned short*)p + i);
        float4 r;
        r.x = bf2f(u.x & 0xffffu); r.y = bf2f(u.x >> 16);
        r.z = bf2f(u.y & 0xffffu); r.w = bf2f(u.y >> 16);
        return r;
    }
    return *(const float4*)((const float*)p + i);
}
__device__ __forceinline__ void stf(void* p, size_t i, float v, int isbf) {
    if (isbf) ((unsigned short*)p)[i] = f2bf(v);
    else      ((float*)p)[i] = v;
}
__device__ __forceinline__ void unpack8(uint4 u, float* f) {
    f[0] = bf2f(u.x & 0xffffu); f[1] = bf2f(u.x >> 16);
    f[2] = bf2f(u.y & 0xffffu); f[3] = bf2f(u.y >> 16);
    f[4] = bf2f(u.z & 0xffffu); f[5] = bf2f(u.z >> 16);
    f[6] = bf2f(u.w & 0xffffu); f[7] = bf2f(u.w >> 16);
}
__device__ __forceinline__ uint4 pack8(const float* f) {
    uint4 u;
    u.x = (unsigned)f2bf(f[0]) | ((unsigned)f2bf(f[1]) << 16);
    u.y = (unsigned)f2bf(f[2]) | ((unsigned)f2bf(f[3]) << 16);
    u.z = (unsigned)f2bf(f[4]) | ((unsigned)f2bf(f[5]) << 16);
    u.w = (unsigned)f2bf(f[6]) | ((unsigned)f2bf(f[7]) << 16);
    return u;
}

// ---------------------------------------------------------------------------
// Dtype probe (proven): bits[8:15] of first 256 words.
// ---------------------------------------------------------------------------
__global__ __launch_bounds__(256) void probe_dtype_kernel(
    const unsigned int* __restrict__ x, int* __restrict__ flag)
{
    __shared__ int cnt;
    if (threadIdx.x == 0) cnt = 0;
    __syncthreads();
    unsigned int b = (x[threadIdx.x] >> 8) & 0x7fu;
    if (b >= 60u && b <= 65u) atomicAdd(&cnt, 1);
    __syncthreads();
    if (threadIdx.x == 0) *flag = (cnt >= 128) ? 1 : 0;
}

// ---------------------------------------------------------------------------
// Prep: Wt[g][n][k] = bf16(W_g[k][n]); block 32 packs f32 tables for
// LN weights (lnwbf[256] = {w,b}) and w_hl (whlf[256]).
// ---------------------------------------------------------------------------
__global__ __launch_bounds__(256) void prep_wt_kernel(
    const void* __restrict__ Wq, const void* __restrict__ Wk,
    const void* __restrict__ Wv, const void* __restrict__ Ws,
    const void* __restrict__ lnw, const void* __restrict__ lnb,
    const void* __restrict__ whl,
    unsigned short* __restrict__ Wt, float* __restrict__ lnwbf,
    float* __restrict__ whlf, const int* __restrict__ dflag)
{
    const int isbf = *dflag;
    if (blockIdx.x >= 32) {
        int t = threadIdx.x;
        lnwbf[t] = (t < 128) ? ldf(lnw, t, isbf) : ldf(lnb, t - 128, isbf);
        whlf[t] = ldf(whl, t, isbf);
        return;
    }
    const int g = blockIdx.x >> 3;
    const int slice = blockIdx.x & 7;
    const void* W = (g == 0) ? Wq : (g == 1) ? Wk : (g == 2) ? Wv : Ws;
    #pragma unroll
    for (int i = 0; i < 8; ++i) {
        int linear = i * 256 + threadIdx.x;
        int k = slice * 16 + (linear >> 7);
        int n = linear & 127;
        float v = ldf(W, (size_t)k * 128 + n, isbf);
        Wt[((size_t)g * 128 + n) * 128 + k] = f2bf(v);
    }
}

// ---------------------------------------------------------------------------
// MFMA projection GEMM. q,k,v -> bf16 qkv[M,384]; skip -> bf16 accv[M,128]
// (bf16 skip: halves write+read traffic; LN output later overlays in place).
// ---------------------------------------------------------------------------
__global__ __launch_bounds__(256) void gemm_mfma_kernel(
    const void* __restrict__ x, const unsigned short* __restrict__ Wt,
    const void* __restrict__ bq, const void* __restrict__ bk,
    const void* __restrict__ bv, const void* __restrict__ bs,
    unsigned short* __restrict__ qkv, unsigned short* __restrict__ accv,
    const int* __restrict__ dflag)
{
    __shared__ unsigned short As[64 * 136];
    __shared__ unsigned short Bs[128 * 136];
    const int isbf = *dflag;
    const int tid = threadIdx.x;
    const int m0 = blockIdx.x * 64;

    #pragma unroll
    for (int i = 0; i < 8; ++i) {
        int linear = i * 256 + tid;
        int row = linear >> 5;
        int c4 = (linear & 31) << 2;
        float4 v = load4f(x, (size_t)(m0 + row) * 128 + c4, isbf);
        ushort4 s;
        s.x = f2bf(v.x); s.y = f2bf(v.y); s.z = f2bf(v.z); s.w = f2bf(v.w);
        *(ushort4*)&As[row * 136 + c4] = s;
    }

    const void* blist[4] = { bq, bk, bv, bs };

    const int lane = tid & 63;
    const int w = tid >> 6;
    const int wm = (w & 1) * 32;
    const int wn = (w >> 1) * 64;
    const int lr = lane & 15;
    const int lk = (lane >> 4) * 8;
    const int rbase = (lane >> 4) * 4;

    for (int c = 0; c < 4; ++c) {
        __syncthreads();
        #pragma unroll
        for (int i = 0; i < 8; ++i) {
            int linear = i * 256 + tid;
            int n = linear >> 4;
            int c8 = (linear & 15) << 3;
            uint4 v = *(const uint4*)&Wt[((size_t)c * 128 + n) * 128 + c8];
            *(uint4*)&Bs[n * 136 + c8] = v;
        }
        __syncthreads();

        f32x4 acc[2][4];
        #pragma unroll
        for (int a = 0; a < 2; ++a)
            #pragma unroll
            for (int b = 0; b < 4; ++b) acc[a][b] = (f32x4){0.f, 0.f, 0.f, 0.f};

        #pragma unroll
        for (int kk = 0; kk < 4; ++kk) {
            int k0 = kk * 32 + lk;
            bf16x8 af[2], bfv[4];
            #pragma unroll
            for (int im = 0; im < 2; ++im)
                af[im] = *(const bf16x8*)&As[(wm + im * 16 + lr) * 136 + k0];
            #pragma unroll
            for (int in = 0; in < 4; ++in)
                bfv[in] = *(const bf16x8*)&Bs[(wn + in * 16 + lr) * 136 + k0];
            #pragma unroll
            for (int im = 0; im < 2; ++im)
                #pragma unroll
                for (int in = 0; in < 4; ++in)
                    acc[im][in] = __builtin_amdgcn_mfma_f32_16x16x32_bf16(
                        af[im], bfv[in], acc[im][in], 0, 0, 0);
        }

        float bias[4];
        #pragma unroll
        for (int in = 0; in < 4; ++in) bias[in] = ldf(blist[c], wn + in * 16 + lr, isbf);

        #pragma unroll
        for (int im = 0; im < 2; ++im) {
            #pragma unroll
            for (int r = 0; r < 4; ++r) {
                int m = wm + im * 16 + rbase + r;
                size_t row = (size_t)(m0 + m);
                #pragma unroll
                for (int in = 0; in < 4; ++in) {
                    int n = wn + in * 16 + lr;
                    float val = acc[im][in][r] + bias[in];
                    if (c < 3) qkv[row * 384 + c * 128 + n] = f2bf(val);
                    else       accv[row * 128 + n] = f2bf(val);
                }
            }
        }
    }
}

// ---------------------------------------------------------------------------
// CSR build: count degrees -> exclusive scan -> fill.
// ---------------------------------------------------------------------------
__global__ __launch_bounds__(256) void count_deg_kernel(
    const int* __restrict__ ei, int E, int* __restrict__ deg)
{
    int e = blockIdx.x * 256 + threadIdx.x;
    if (e >= E) return;
    atomicAdd(&deg[ei[E + e]], 1);
}

__global__ __launch_bounds__(256) void scan1_kernel(
    const int* __restrict__ deg, int* __restrict__ pre, int* __restrict__ bsum)
{
    __shared__ int wsum[4];
    int tid = threadIdx.x;
    int lane = tid & 63, w = tid >> 6;
    int base = blockIdx.x * 1024 + tid * 4;
    int4 v = *(const int4*)(deg + base);
    int s = v.x + v.y + v.z + v.w;
    int inc = s;
    #pragma unroll
    for (int m = 1; m < 64; m <<= 1) {
        int t = __shfl_up(inc, m, 64);
        if (lane >= m) inc += t;
    }
    if (lane == 63) wsum[w] = inc;
    __syncthreads();
    int woff = 0;
    #pragma unroll
    for (int j = 0; j < 4; ++j) if (j < w) woff += wsum[j];
    int excl = woff + inc - s;
    pre[base]     = excl;
    pre[base + 1] = excl + v.x;
    pre[base + 2] = excl + v.x + v.y;
    pre[base + 3] = excl + v.x + v.y + v.z;
    if (tid == 0) bsum[blockIdx.x] = wsum[0] + wsum[1] + wsum[2] + wsum[3];
}

__global__ void scan2_kernel(int* __restrict__ bsum, int NB)
{
    if (threadIdx.x == 0 && blockIdx.x == 0) {
        int run = 0;
        for (int i = 0; i < NB; ++i) { int t = bsum[i]; bsum[i] = run; run += t; }
    }
}

__global__ __launch_bounds__(256) void scan3_kernel(
    const int* __restrict__ pre, const int* __restrict__ bsum,
    int* __restrict__ off, int N)
{
    int i = blockIdx.x * 256 + threadIdx.x;
    if (i >= N) return;
    off[i] = pre[i] + bsum[i >> 10];
}

__global__ __launch_bounds__(256) void fill_csr_kernel(
    const int* __restrict__ ei, int E, int* __restrict__ off,
    int* __restrict__ csr)
{
    int e = blockIdx.x * 256 + threadIdx.x;
    if (e >= E) return;
    int dst = ei[E + e];
    int pos = atomicAdd(&off[dst], 1);
    csr[pos] = ei[e];
}

// ---------------------------------------------------------------------------
// Fused gather attention + skip + LayerNorm + ReLU, quarter-wave layout:
// 16 lanes per node (8 dims/lane, 16B loads), 4 nodes/wave, 16 nodes/block.
// Head h = lanes [4h,4h+4); per-head score reduce is xor-1/2 over the 4-lane
// group (all 16 lanes of a node share cnt, so shuffles stay convergent).
// skip_out is bf16 [N][128]: skip read, then LN'd output written in place
// (same lane reads its 16B before writing them — program order safe).
// ---------------------------------------------------------------------------
__global__ __launch_bounds__(256) void attn_gather_ln_kernel(
    const unsigned short* __restrict__ qkv, const int* __restrict__ csr_src,
    const int* __restrict__ off_end, const int* __restrict__ deg,
    unsigned short* skip_out, const float* __restrict__ lnwbf, int N)
{
    int il = threadIdx.x & 15;
    int n = blockIdx.x * 16 + (threadIdx.x >> 4);
    if (n >= N) return;
    int end = off_end[n];
    int cnt = deg[n];
    int p = end - cnt;

    float qf[8];
    unpack8(*(const uint4*)(qkv + (long)n * 384 + 8 * il), qf);
    float acc[8] = {0.f, 0.f, 0.f, 0.f, 0.f, 0.f, 0.f, 0.f};
    float den = 0.f;

    int it = 0;
    for (; it + 1 < cnt; it += 2) {
        int s0 = csr_src[p + it];
        int s1 = csr_src[p + it + 1];
        const unsigned short* b0 = qkv + (long)s0 * 384 + 8 * il;
        const unsigned short* b1 = qkv + (long)s1 * 384 + 8 * il;
        uint4 k0w = *(const uint4*)(b0 + 128);
        uint4 v0w = *(const uint4*)(b0 + 256);
        uint4 k1w = *(const uint4*)(b1 + 128);
        uint4 v1w = *(const uint4*)(b1 + 256);
        float kf[8], vf[8], kg[8], vg[8];
        unpack8(k0w, kf); unpack8(v0w, vf);
        unpack8(k1w, kg); unpack8(v1w, vg);
        float p0 = 0.f, p1 = 0.f;
        #pragma unroll
        for (int j = 0; j < 8; ++j) { p0 += qf[j] * kf[j]; p1 += qf[j] * kg[j]; }
        p0 += __shfl_xor(p0, 1, 64); p1 += __shfl_xor(p1, 1, 64);
        p0 += __shfl_xor(p0, 2, 64); p1 += __shfl_xor(p1, 2, 64);
        float e0 = __expf(fminf(fmaxf(p0 * ATT_SCALE, -60.f), 60.f));
        float e1 = __expf(fminf(fmaxf(p1 * ATT_SCALE, -60.f), 60.f));
        den += e0 + e1;
        #pragma unroll
        for (int j = 0; j < 8; ++j) acc[j] += e0 * vf[j] + e1 * vg[j];
    }
    if (it < cnt) {
        int s0 = csr_src[p + it];
        const unsigned short* b0 = qkv + (long)s0 * 384 + 8 * il;
        uint4 k0w = *(const uint4*)(b0 + 128);
        uint4 v0w = *(const uint4*)(b0 + 256);
        float kf[8], vf[8];
        unpack8(k0w, kf); unpack8(v0w, vf);
        float p0 = 0.f;
        #pragma unroll
        for (int j = 0; j < 8; ++j) p0 += qf[j] * kf[j];
        p0 += __shfl_xor(p0, 1, 64);
        p0 += __shfl_xor(p0, 2, 64);
        float e0 = __expf(fminf(fmaxf(p0 * ATT_SCALE, -60.f), 60.f));
        den += e0;
        #pragma unroll
        for (int j = 0; j < 8; ++j) acc[j] += e0 * vf[j];
    }

    float inv = (cnt > 0) ? 1.f / den : 0.f;
    float x[8];
    unpack8(*(const uint4*)(skip_out + (long)n * 128 + 8 * il), x);
    float s = 0.f, qq = 0.f;
    #pragma unroll
    for (int j = 0; j < 8; ++j) {
        x[j] = acc[j] * inv + x[j];
        s += x[j];
        qq += x[j] * x[j];
    }
    #pragma unroll
    for (int m = 1; m < 16; m <<= 1) {
        s += __shfl_xor(s, m, 64);
        qq += __shfl_xor(qq, m, 64);
    }
    float mean = s * (1.f / 128.f);
    float var = fmaxf(qq * (1.f / 128.f) - mean * mean, 0.f);
    float rs = rsqrtf(var + LN_EPS);
    float4 wA = *(const float4*)(lnwbf + 8 * il);
    float4 wB = *(const float4*)(lnwbf + 8 * il + 4);
    float4 bA = *(const float4*)(lnwbf + 128 + 8 * il);
    float4 bB = *(const float4*)(lnwbf + 128 + 8 * il + 4);
    float wv[8] = {wA.x, wA.y, wA.z, wA.w, wB.x, wB.y, wB.z, wB.w};
    float bv[8] = {bA.x, bA.y, bA.z, bA.w, bB.x, bB.y, bB.z, bB.w};
    float y[8];
    #pragma unroll
    for (int j = 0; j < 8; ++j)
        y[j] = fmaxf((x[j] - mean) * rs * wv[j] + bv[j], 0.f);
    *(uint4*)(skip_out + (long)n * 128 + 8 * il) = pack8(y);
}

// ---------------------------------------------------------------------------
// global_mean_pool; l is dense bf16 [N][128] now; 4-unrolled streaming sum.
// ---------------------------------------------------------------------------
__global__ __launch_bounds__(128) void pool_kernel(
    const unsigned short* __restrict__ l, const int* __restrict__ batch,
    float* __restrict__ pooled)
{
    __shared__ int se[2];
    int g = blockIdx.x;
    if (threadIdx.x == 0) {
        int lo = 0, hi = N_LOW;
        while (lo < hi) { int mid = (lo + hi) >> 1; if (batch[mid] < g) lo = mid + 1; else hi = mid; }
        se[0] = lo;
        hi = N_LOW;
        while (lo < hi) { int mid = (lo + hi) >> 1; if (batch[mid] < g + 1) lo = mid + 1; else hi = mid; }
        se[1] = lo;
    }
    __syncthreads();
    int start = se[0], end = se[1];
    int d = threadIdx.x;
    float s0 = 0.f, s1 = 0.f, s2 = 0.f, s3 = 0.f;
    int r = start;
    for (; r + 3 < end; r += 4) {
        s0 += bf2f(l[(long)r * 128 + d]);
        s1 += bf2f(l[(long)(r + 1) * 128 + d]);
        s2 += bf2f(l[(long)(r + 2) * 128 + d]);
        s3 += bf2f(l[(long)(r + 3) * 128 + d]);
    }
    for (; r < end; ++r) s0 += bf2f(l[(long)r * 128 + d]);
    int cnt = end - start;
    pooled[(long)g * 128 + d] = ((s0 + s1) + (s2 + s3)) / (float)(cnt > 0 ? cnt : 1);
}

// ---------------------------------------------------------------------------
// high_out = sim*h + (1-sim)*pooled (h now dense [N][128] bf16)
// ---------------------------------------------------------------------------
__global__ __launch_bounds__(256) void high_out_kernel(
    const unsigned short* __restrict__ h, const float* __restrict__ pooled,
    const void* __restrict__ wlh, void* __restrict__ out,
    const int* __restrict__ dflag)
{
    const int isbf = *dflag;
    int lane = threadIdx.x & 63;
    int n = blockIdx.x * 4 + (threadIdx.x >> 6);
    if (n >= N_HIGH) return;
    float h0 = bf2f(h[(long)n * 128 + 2 * lane]);
    float h1 = bf2f(h[(long)n * 128 + 2 * lane + 1]);
    float2 pv = *(const float2*)(pooled + (long)n * 128 + 2 * lane);
    float s = h0 * ldf(wlh, 2 * lane, isbf) + h1 * ldf(wlh, 2 * lane + 1, isbf)
            + pv.x * ldf(wlh, 128 + 2 * lane, isbf) + pv.y * ldf(wlh, 128 + 2 * lane + 1, isbf);
    #pragma unroll
    for (int m = 1; m < 64; m <<= 1) s += __shfl_xor(s, m, 64);
    float sim = 1.f / (1.f + __expf(-s));
    stf(out, (size_t)n * 128 + 2 * lane,     sim * h0 + (1.f - sim) * pv.x, isbf);
    stf(out, (size_t)n * 128 + 2 * lane + 1, sim * h1 + (1.f - sim) * pv.y, isbf);
}

// ---------------------------------------------------------------------------
// low_out = a*l + (1-a)*h[batch], quarter-wave: 16 lanes/node, 8 dims/lane.
// ---------------------------------------------------------------------------
__global__ __launch_bounds__(256) void low_out_kernel(
    const unsigned short* __restrict__ l, const unsigned short* __restrict__ h,
    const int* __restrict__ batch, const float* __restrict__ whlf,
    void* __restrict__ out, const int* __restrict__ dflag)
{
    const int isbf = *dflag;
    int il = threadIdx.x & 15;
    int n = blockIdx.x * 16 + (threadIdx.x >> 4);
    if (n >= N_LOW) return;
    int g = batch[n];
    float lf[8], hf[8];
    unpack8(*(const uint4*)(l + (long)n * 128 + 8 * il), lf);
    unpack8(*(const uint4*)(h + (long)g * 128 + 8 * il), hf);
    float4 wh0 = *(const float4*)(whlf + 8 * il);
    float4 wh1 = *(const float4*)(whlf + 8 * il + 4);
    float4 wl0 = *(const float4*)(whlf + 128 + 8 * il);
    float4 wl1 = *(const float4*)(whlf + 128 + 8 * il + 4);
    float s = hf[0] * wh0.x + hf[1] * wh0.y + hf[2] * wh0.z + hf[3] * wh0.w
            + hf[4] * wh1.x + hf[5] * wh1.y + hf[6] * wh1.z + hf[7] * wh1.w
            + lf[0] * wl0.x + lf[1] * wl0.y + lf[2] * wl0.z + lf[3] * wl0.w
            + lf[4] * wl1.x + lf[5] * wl1.y + lf[6] * wl1.z + lf[7] * wl1.w;
    #pragma unroll
    for (int m = 1; m < 16; m <<= 1) s += __shfl_xor(s, m, 64);
    float a = 1.f / (1.f + __expf(-s));
    float y[8];
    #pragma unroll
    for (int j = 0; j < 8; ++j) y[j] = a * lf[j] + (1.f - a) * hf[j];
    size_t base = (size_t)N_HIGH * 128 + (size_t)n * 128 + 8 * il;
    if (isbf) {
        *(uint4*)((unsigned short*)out + base) = pack8(y);
    } else {
        float* o = (float*)out + base;
        *(float4*)o       = (float4){y[0], y[1], y[2], y[3]};
        *(float4*)(o + 4) = (float4){y[4], y[5], y[6], y[7]};
    }
}

// ---------------------------------------------------------------------------
extern "C" void kernel_launch(void* const* d_in, const int* in_sizes, int n_in,
                              void* d_out, int out_size, void* d_ws, size_t ws_size,
                              hipStream_t stream)
{
    const void* high_emb = d_in[0];
    const void* low_emb  = d_in[1];
    const void* Wq = d_in[2];  const void* bq = d_in[3];
    const void* Wk = d_in[4];  const void* bk = d_in[5];
    const void* Wv = d_in[6];  const void* bv = d_in[7];
    const void* Ws = d_in[8];  const void* bs = d_in[9];
    const void* ln_w = d_in[10];
    const void* ln_b = d_in[11];
    const void* w_lh = d_in[12];
    const void* w_hl = d_in[13];
    const int* ei_high = (const int*)d_in[14];
    const int* ei_low  = (const int*)d_in[15];
    const int* batch   = (const int*)d_in[16];

    // Workspace layout (bytes). WS_NEEDED unchanged from the proven layout.
    char* ws = (char*)d_ws;
    const size_t OFF_QKV_LOW  = 0;           // bf16 [N_LOW,384]
    const size_t OFF_ACC_LOW  = 201326592;   // bf16 skip [N_LOW,128]; LN'd l overlays in place
    const size_t OFF_AUX      = 335544320;   // Wt + f32 tables + CSR scratch
    const size_t OFF_QKV_HIGH = 348127232;   // bf16 [N_HIGH,384]
    const size_t OFF_ACC_HIGH = 351272960;   // bf16 skip [N_HIGH,128]; LN'd h overlays in place
    const size_t OFF_POOLED   = 354484224;   // f32 [N_HIGH,128]
    const size_t OFF_FLAG     = 356581376;   // int dtype flag
    const size_t WS_NEEDED    = 356581632;
    if (ws_size < WS_NEEDED) return;

    unsigned short* qkv_low  = (unsigned short*)(ws + OFF_QKV_LOW);
    unsigned short* acc_low  = (unsigned short*)(ws + OFF_ACC_LOW);
    unsigned short* qkv_high = (unsigned short*)(ws + OFF_QKV_HIGH);
    unsigned short* acc_high = (unsigned short*)(ws + OFF_ACC_HIGH);
    float*          pooled   = (float*)(ws + OFF_POOLED);
    int*            dflag    = (int*)(ws + OFF_FLAG);

    // AUX region carve-up (all 16B aligned):
    unsigned short* Wt    = (unsigned short*)(ws + OFF_AUX);   // 131072 B used
    float* lnwbf = (float*)(ws + OFF_AUX + 131072);            // 1 KB (w[128],b[128])
    float* whlf  = (float*)(ws + OFF_AUX + 132096);            // 1 KB
    int* deg_low  = (int*)(ws + OFF_AUX +  262144);            // 1 MB
    int* pre_low  = (int*)(ws + OFF_AUX + 1310720);            // 1 MB
    int* off_low  = (int*)(ws + OFF_AUX + 2359296);            // 1 MB
    int* csr_low  = (int*)(ws + OFF_AUX + 3407872);            // 2 MB
    int* deg_high = (int*)(ws + OFF_AUX + 5505024);            // 16 KB
    int* pre_high = (int*)(ws + OFF_AUX + 5521408);            // 16 KB
    int* off_high = (int*)(ws + OFF_AUX + 5537792);            // 16 KB
    int* csr_high = (int*)(ws + OFF_AUX + 5554176);            // 256 KB
    int* bsum     = (int*)(ws + OFF_AUX + 5816320);            // 4 KB

    unsigned short* l_low  = acc_low;   // LN output overlays skip buffer
    unsigned short* h_high = acc_high;

    hipMemsetAsync(deg_low, 0, (size_t)N_LOW * sizeof(int), stream);
    hipMemsetAsync(deg_high, 0, (size_t)N_HIGH * sizeof(int), stream);

    probe_dtype_kernel<<<1, 256, 0, stream>>>((const unsigned int*)high_emb, dflag);

    // CSR build
    count_deg_kernel<<<E_LOW / 256, 256, 0, stream>>>(ei_low, E_LOW, deg_low);
    count_deg_kernel<<<E_HIGH / 256, 256, 0, stream>>>(ei_high, E_HIGH, deg_high);

    scan1_kernel<<<N_LOW / 1024, 256, 0, stream>>>(deg_low, pre_low, bsum);
    scan2_kernel<<<1, 64, 0, stream>>>(bsum, N_LOW / 1024);
    scan3_kernel<<<N_LOW / 256, 256, 0, stream>>>(pre_low, bsum, off_low, N_LOW);

    scan1_kernel<<<N_HIGH / 1024, 256, 0, stream>>>(deg_high, pre_high, bsum);
    scan2_kernel<<<1, 64, 0, stream>>>(bsum, N_HIGH / 1024);
    scan3_kernel<<<N_HIGH / 256, 256, 0, stream>>>(pre_high, bsum, off_high, N_HIGH);

    fill_csr_kernel<<<E_LOW / 256, 256, 0, stream>>>(ei_low, E_LOW, off_low, csr_low);
    fill_csr_kernel<<<E_HIGH / 256, 256, 0, stream>>>(ei_high, E_HIGH, off_high, csr_high);
    // off_* now holds END offsets; start = end - deg.

    prep_wt_kernel<<<33, 256, 0, stream>>>(Wq, Wk, Wv, Ws, ln_w, ln_b, w_hl,
                                           Wt, lnwbf, whlf, dflag);

    gemm_mfma_kernel<<<N_HIGH / 64, 256, 0, stream>>>(
        high_emb, Wt, bq, bk, bv, bs, qkv_high, acc_high, dflag);
    gemm_mfma_kernel<<<N_LOW / 64, 256, 0, stream>>>(
        low_emb, Wt, bq, bk, bv, bs, qkv_low, acc_low, dflag);

    attn_gather_ln_kernel<<<N_HIGH / 16, 256, 0, stream>>>(
        qkv_high, csr_high, off_high, deg_high, acc_high, lnwbf, N_HIGH);
    attn_gather_ln_kernel<<<N_LOW / 16, 256, 0, stream>>>(
        qkv_low, csr_low, off_low, deg_low, acc_low, lnwbf, N_LOW);

    pool_kernel<<<N_HIGH, 128, 0, stream>>>(l_low, batch, pooled);

    high_out_kernel<<<N_HIGH / 4, 256, 0, stream>>>(h_high, pooled, w_lh, d_out, dflag);
    low_out_kernel<<<N_LOW / 16, 256, 0, stream>>>(l_low, h_high, batch, whlf, d_out, dflag);
}